// Round 21
// baseline (56.863 us; speedup 1.0000x reference)
//
#include <hip/hip_runtime.h>
#include <math.h>

#define NN 8192
#define DD 256
#define MARGIN 0.2f
#define SL 16                // candidate slices (grid.x)
#define CPS (NN / SL)        // 512 candidates per slice
#define TILES (CPS / 64)     // 8 tiles per block (64 rows each)
#define IMAX 0x7fffffff

typedef __attribute__((ext_vector_type(4))) float f32x4;
typedef __attribute__((ext_vector_type(2))) long long2_t;
typedef __attribute__((ext_vector_type(8))) int i32x8;
typedef unsigned int u32;
typedef unsigned char u8;

// ---- software RNE fp32 -> OCP e4m3fn (no inf; max 448; bias 7) ----
static __device__ __forceinline__ u8 f2e4m3(float x) {
    float a = fabsf(x);
    a = fminf(a, 448.0f);
    const u32 s = (__float_as_uint(x) >> 31) << 7;
    if (a < 0.015625f) {                      // subnormal range: step 2^-9
        const int m = (int)rintf(a * 512.0f); // 0..8 (8 carries into exp=1 naturally)
        return (u8)(s | m);
    }
    u32 u = __float_as_uint(a);
    u += 0x7FFFF + ((u >> 20) & 1);           // RNE into 3-bit mantissa
    const u32 e = (u >> 23) - 120;            // -127 + 7
    return (u8)(s | (e << 3) | ((u >> 20) & 7));
}

static __device__ __forceinline__ i32x8 pack8(long2_t lo, long2_t hi) {
    union { long2_t l2[2]; i32x8 v; } u;
    u.l2[0] = lo; u.l2[1] = hi;
    return u.v;
}

// builtin's size/offset must be LITERAL constants
#define GLOAD16(g, l)                                                             \
    __builtin_amdgcn_global_load_lds(                                             \
        (const __attribute__((address_space(1))) void*)(g),                       \
        (__attribute__((address_space(3))) void*)(l), 16, 0, 0)

// ---------- kernel 1: fused kprep (blocks 0..2047) + kclass (2048..2175) ----------
static __device__ __forceinline__ void comb2(int& a1, int& a2, int b1, int b2) {
    const int lo = min(a1, b1);
    const int hi = max(a1, b1);
    a2 = min(hi, min(a2, b2));
    a1 = lo;
}

__global__ void kprepclass(const float* __restrict__ emb, const int* __restrict__ labels,
                           u8* __restrict__ E8, float* __restrict__ invn,
                           int* __restrict__ posidx, u32* __restrict__ cnt_done) {
    const int tid = threadIdx.x;
    if (blockIdx.x < 2048) {   // ---- kprep: normalized fp8 rows (plain layout) ----
        const int wid = tid >> 6, l = tid & 63;
        const int row = blockIdx.x * 4 + wid;
        const float4 v = *(const float4*)&emb[(size_t)row * DD + l * 4];
        float ss = v.x * v.x + v.y * v.y + v.z * v.z + v.w * v.w;
#pragma unroll
        for (int o = 1; o < 64; o <<= 1) ss += __shfl_xor(ss, o);
        const float inv = 1.0f / fmaxf(sqrtf(ss), 1e-12f);
        if (l == 0) invn[row] = inv;
        const u32 b0 = f2e4m3(v.x * inv), b1 = f2e4m3(v.y * inv);
        const u32 b2 = f2e4m3(v.z * inv), b3 = f2e4m3(v.w * inv);
        const u32 packed = b0 | (b1 << 8) | (b2 << 16) | (b3 << 24);
        *(u32*)&E8[(size_t)row * DD + l * 4] = packed;   // linear: A/B read identically
    } else {                   // ---- kclass ----
        const int c = blockIdx.x - 2048;
        if (c == 0 && tid == 0) *cnt_done = 0;   // arm the combine-final counter
        int m1 = IMAX, m2 = IMAX;
        for (int j = tid; j < NN; j += 256) {
            if (labels[j] == c) {
                if (m1 == IMAX) m1 = j;
                else if (m2 == IMAX) m2 = j;
            }
        }
#pragma unroll
        for (int o = 1; o < 64; o <<= 1)
            comb2(m1, m2, __shfl_xor(m1, o), __shfl_xor(m2, o));
        __shared__ int s1[4], s2[4];
        __shared__ int bj1, bj2;
        const int wave = tid >> 6, lane = tid & 63;
        if (lane == 0) { s1[wave] = m1; s2[wave] = m2; }
        __syncthreads();
        if (tid == 0) {
            comb2(m1, m2, s1[1], s2[1]);
            comb2(m1, m2, s1[2], s2[2]);
            comb2(m1, m2, s1[3], s2[3]);
            bj1 = m1; bj2 = m2;
        }
        __syncthreads();
        const int j1 = bj1, j2 = bj2;
        for (int j = tid; j < NN; j += 256)
            if (labels[j] == c) posidx[j] = (j2 == IMAX) ? -1 : ((j == j1) ? j2 : j1);
    }
}

// ---------- kernel 3: exact fp32 d_ap ----------
__global__ void kdap(const float* __restrict__ emb, const float* __restrict__ invn,
                     const int* __restrict__ posidx, float* __restrict__ dap) {
    const int wid = threadIdx.x >> 6, l = threadIdx.x & 63;
    const int i = blockIdx.x * 4 + wid;
    const int p = posidx[i];
    float dv = 0.0f;
    if (p >= 0) {   // uniform per wave
        const float4 a = *(const float4*)&emb[(size_t)i * DD + l * 4];
        const float4 b = *(const float4*)&emb[(size_t)p * DD + l * 4];
        float s = a.x * b.x + a.y * b.y + a.z * b.z + a.w * b.w;
#pragma unroll
        for (int o = 1; o < 64; o <<= 1) s += __shfl_xor(s, o);
        const float sim = s * invn[i] * invn[p];
        dv = fminf(fmaxf(1.0f - sim, 0.0f), 2.0f);
    }
    if (l == 0) dap[i] = dv;
}

// ---------- kernel 4: MX-scaled fp8 MFMA mining — barrier-free wave-private DMA ----
// Each wave stages ITS OWN 32 candidate rows per tile into a private LDS double
// buffer via global_load_lds; counted vmcnt on the wave's own DMAs replaces all
// main-loop barriers (R20 proved DMA depth isn't the stall; the barrier lockstep
// is). Layout identity: lane l, issue i writes base+i*1024+l*16 == row*256+P*16
// with row=(l>>4)+4i, P=l&15 -> same linear-row + P=C^(row&15) swizzle as R19
// (0 conflicts measured). Per-wave fragment/epilogue/reduction verbatim R19.
__global__ __launch_bounds__(256) void kmine(
    const u8* __restrict__ E8, const int* __restrict__ labels,
    const float* __restrict__ dap, float* __restrict__ pM1, float* __restrict__ pMN)
{
    __shared__ __align__(16) u8 Ab[4][2][32 * 256];   // per-wave private dbuf, 64 KB
    __shared__ __align__(16) int Ls[CPS];             // 2 KB labels
    __shared__ float RedN[2][128], RedS[2][128];

    const int tid = threadIdx.x;
    const int l = tid & 63;
    const int wid = tid >> 6;
    const int wr = wid >> 1;      // candidate half: rows wr*32..
    const int wc = wid & 1;       // anchor half: anchors wc*64..
    const int slice = blockIdx.x;
    const int a0 = blockIdx.y * 128;
    const int c0 = slice * CPS;

    const int frow = l & 15;      // row within 16x16 subtile
    const int fq = l >> 4;        // 32-B k-group 0..3 within a K=128 half

    // --- prologue: labels -> LDS, per-anchor consts, B -> registers ---
    if (tid < 128) {
        const int4 lv = *(const int4*)&labels[c0 + tid * 4];
        *(int4*)&Ls[tid * 4] = lv;
    }
    int la[4]; float hiv[4];
#pragma unroll
    for (int n = 0; n < 4; ++n) {
        const int ai = a0 + wc * 64 + n * 16 + frow;
        la[n] = labels[ai];
        hiv[n] = 1.0f - dap[ai];
    }
    const char* Ec = (const char*)E8;
    i32x8 breg[4][2];             // [n][kh] -> 64 VGPR
#pragma unroll
    for (int n = 0; n < 4; ++n)
#pragma unroll
        for (int kh = 0; kh < 2; ++kh) {
            const char* p = Ec + (size_t)(a0 + wc * 64 + n * 16 + frow) * 256
                               + kh * 128 + fq * 32;
            breg[n][kh] = pack8(*(const long2_t*)p, *(const long2_t*)(p + 16));
        }

    // wave-private staging geometry: lane l, issue i covers local row r=(l>>4)+4i,
    // physical chunk P=l&15, source chunk C = P ^ (r&15). 8 issues = 8 KB tile.
    const int rl = l >> 4;        // 0..3
    const int cp = l & 15;
    int soff[4];                  // source offsets for issues j and j+4 (+4096)
#pragma unroll
    for (int j = 0; j < 4; ++j) {
        const int r = rl + 4 * j;
        soff[j] = r * 256 + ((cp ^ (r & 15)) * 16);
    }
    const char* wbase = Ec + (size_t)(c0 + wr * 32) * 256;   // wave rows, tile 0
    u8* buf0 = &Ab[wid][0][0];
    u8* buf1 = &Ab[wid][1][0];

#define STAGE(BUF, TOFF) do {                                        \
        _Pragma("unroll")                                            \
        for (int i = 0; i < 8; ++i)                                  \
            GLOAD16(wbase + (TOFF) + soff[i & 3] + (i >> 2) * 4096,  \
                    (BUF) + i * 1024 + l * 16);                      \
    } while (0)

    float mN[4], m1[4];
#pragma unroll
    for (int n = 0; n < 4; ++n) { mN[n] = -INFINITY; m1[n] = -INFINITY; }
    const f32x4 Zv = {0.f, 0.f, 0.f, 0.f};
    f32x4 acc[2][4];

    // compute this wave's 32-row x 64-anchor tile (K=256 = 2 scaled-MFMA) + maxes
#define COMPTILE(BUF, T) do {                                                       \
        _Pragma("unroll")                                                           \
        for (int kh = 0; kh < 2; ++kh) {                                            \
            i32x8 a8[2];                                                            \
            _Pragma("unroll")                                                       \
            for (int m = 0; m < 2; ++m) {                                           \
                const int lr = m * 16 + frow;                                       \
                const int cb = kh * 8 + fq * 2;                                     \
                const int p0 = (cb ^ frow) * 16;                                    \
                const int p1 = ((cb + 1) ^ frow) * 16;                              \
                a8[m] = pack8(*(const long2_t*)&(BUF)[lr * 256 + p0],               \
                              *(const long2_t*)&(BUF)[lr * 256 + p1]);              \
            }                                                                       \
            __builtin_amdgcn_s_setprio(1);                                          \
            _Pragma("unroll")                                                       \
            for (int m = 0; m < 2; ++m)                                             \
                _Pragma("unroll")                                                   \
                for (int n = 0; n < 4; ++n)                                         \
                    acc[m][n] = __builtin_amdgcn_mfma_scale_f32_16x16x128_f8f6f4(   \
                        a8[m], breg[n][kh], (kh == 0) ? Zv : acc[m][n],             \
                        0, 0, 0, 0x7F7F7F7F, 0, 0x7F7F7F7F);                        \
            __builtin_amdgcn_s_setprio(0);                                          \
        }                                                                           \
        {                                                                           \
            int lcv[8];                                                             \
            _Pragma("unroll")                                                       \
            for (int m = 0; m < 2; ++m) {                                           \
                const int4 v = *(const int4*)&Ls[(T) * 64 + wr * 32 + m * 16        \
                                                 + fq * 4];                        \
                lcv[m * 4 + 0] = v.x; lcv[m * 4 + 1] = v.y;                         \
                lcv[m * 4 + 2] = v.z; lcv[m * 4 + 3] = v.w;                         \
            }                                                                       \
            _Pragma("unroll")                                                       \
            for (int n = 0; n < 4; ++n) {                                           \
                _Pragma("unroll")                                                   \
                for (int m = 0; m < 2; ++m)                                         \
                    _Pragma("unroll")                                               \
                    for (int r = 0; r < 4; ++r) {                                   \
                        const float sv = acc[m][n][r];                              \
                        const float sel = (lcv[m * 4 + r] != la[n]) ? sv            \
                                                                    : -INFINITY;    \
                        mN[n] = fmaxf(mN[n], sel);                                  \
                        m1[n] = fmaxf(m1[n], (sel < hiv[n]) ? sel : -INFINITY);     \
                    }                                                               \
            }                                                                       \
        }                                                                           \
    } while (0)

    // prologue: stage tile 0; labels visible to all waves (single barrier)
    STAGE(buf0, 0);
    asm volatile("s_waitcnt lgkmcnt(0)" ::: "memory");
    __builtin_amdgcn_s_barrier();

#pragma unroll
    for (int t = 0; t < TILES; ++t) {
        if (t + 1 < TILES) {
            if (t & 1) STAGE(buf0, (t + 1) * 16384);
            else       STAGE(buf1, (t + 1) * 16384);
            asm volatile("s_waitcnt vmcnt(8)" ::: "memory");   // own stage(t) landed
        } else {
            asm volatile("s_waitcnt vmcnt(0)" ::: "memory");
        }
        if (t & 1) COMPTILE(buf1, t);
        else       COMPTILE(buf0, t);
        // no barrier: buffers are wave-private; ds_reads retire before next DMA lands
    }
#undef STAGE
#undef COMPTILE

    // reduce the 4 candidate row-groups (lanes l, l^16, l^32, l^48 share anchor)
#pragma unroll
    for (int n = 0; n < 4; ++n) {
        mN[n] = fmaxf(mN[n], __shfl_xor(mN[n], 16));
        mN[n] = fmaxf(mN[n], __shfl_xor(mN[n], 32));
        m1[n] = fmaxf(m1[n], __shfl_xor(m1[n], 16));
        m1[n] = fmaxf(m1[n], __shfl_xor(m1[n], 32));
    }
    __syncthreads();
    // combine the two candidate halves via LDS max (wr = 0,1)
    if (fq == 0) {
#pragma unroll
        for (int n = 0; n < 4; ++n) {
            if (wr == 0) {
                RedN[0][wc * 64 + n * 16 + frow] = mN[n];
                RedS[0][wc * 64 + n * 16 + frow] = m1[n];
            } else {
                RedN[1][wc * 64 + n * 16 + frow] = mN[n];
                RedS[1][wc * 64 + n * 16 + frow] = m1[n];
            }
        }
    }
    __syncthreads();
    if (tid < 128) {
        pMN[slice * NN + a0 + tid] = fmaxf(RedN[0][tid], RedN[1][tid]);
        pM1[slice * NN + a0 + tid] = fmaxf(RedS[0][tid], RedS[1][tid]);
    }
}

// ---------- kernel 5: combine slices + fused final scalar ----------
__global__ void kcombine(const int* __restrict__ posidx, const float* __restrict__ dap,
                         const float* __restrict__ pM1, const float* __restrict__ pMN,
                         float* __restrict__ partials, u32* __restrict__ cnt_done,
                         float* __restrict__ out)
{
    const int i = blockIdx.x * 256 + threadIdx.x;
    float loss = 0.0f, cnt = 0.0f;
    if (posidx[i] >= 0) {
        float s1 = -INFINITY, sN = -INFINITY;
#pragma unroll
        for (int s = 0; s < SL; ++s) {
            s1 = fmaxf(s1, pM1[s * NN + i]);
            sN = fmaxf(sN, pMN[s * NN + i]);
        }
        const float da = dap[i];
        const float lo = 1.0f - da - MARGIN;
        const float M = (s1 > lo) ? s1 : sN;   // has_semi ? best semi : hardest
        const float dan = fminf(fmaxf(1.0f - M, 0.0f), 2.0f);
        loss = fmaxf(da - dan + MARGIN, 0.0f);
        cnt = 1.0f;
    }
#pragma unroll
    for (int off = 1; off < 64; off <<= 1) {
        loss += __shfl_xor(loss, off);
        cnt  += __shfl_xor(cnt, off);
    }
    __shared__ float sl[4], sc[4];
    __shared__ int last;
    const int wave = threadIdx.x >> 6, lane = threadIdx.x & 63;
    if (lane == 0) { sl[wave] = loss; sc[wave] = cnt; }
    __syncthreads();
    if (threadIdx.x == 0) {
        partials[blockIdx.x]      = sl[0] + sl[1] + sl[2] + sl[3];
        partials[32 + blockIdx.x] = sc[0] + sc[1] + sc[2] + sc[3];
        __threadfence();
        last = (atomicAdd(cnt_done, 1u) == 31u);   // device-scope, cross-XCD safe
    }
    __syncthreads();
    if (last && threadIdx.x < 64) {   // last block reduces all partials
        const int t = threadIdx.x;
        float L = (t < 32) ? partials[t] : 0.0f;
        float C = (t < 32) ? partials[32 + t] : 0.0f;
#pragma unroll
        for (int off = 1; off < 64; off <<= 1) {
            L += __shfl_xor(L, off);
            C += __shfl_xor(C, off);
        }
        if (t == 0) out[0] = (C > 0.0f) ? (L / C) : 0.0f;
    }
}

extern "C" void kernel_launch(void* const* d_in, const int* in_sizes, int n_in,
                              void* d_out, int out_size, void* d_ws, size_t ws_size,
                              hipStream_t stream) {
    const float* emb  = (const float*)d_in[0];
    const int* labels = (const int*)d_in[1];
    float* out = (float*)d_out;

    char* w = (char*)d_ws;
    u8*    E8   = (u8*)w;                        w += (size_t)NN * DD;       // 2 MB
    float* invn = (float*)w;                     w += NN * 4;
    float* dapv = (float*)w;                     w += NN * 4;
    int*   posi = (int*)w;                       w += NN * 4;
    float* pM1  = (float*)w;                     w += (size_t)SL * NN * 4;   // 512 KB
    float* pMN  = (float*)w;                     w += (size_t)SL * NN * 4;   // 512 KB
    float* parts = (float*)w;                    w += 64 * 4;
    u32*   cdone = (u32*)w;

    kprepclass<<<2048 + 128, 256, 0, stream>>>(emb, labels, E8, invn, posi, cdone);
    kdap<<<NN / 4, 256, 0, stream>>>(emb, invn, posi, dapv);
    kmine<<<dim3(SL, NN / 128), 256, 0, stream>>>(E8, labels, dapv, pM1, pMN);
    kcombine<<<NN / 256, 256, 0, stream>>>(posi, dapv, pM1, pMN, parts, cdone, out);
}

// Round 22
// 54.348 us; speedup vs baseline: 1.0463x; 1.0463x over previous
//
#include <hip/hip_runtime.h>
#include <math.h>

#define NN 8192
#define DD 256
#define MARGIN 0.2f
#define SL 16                // candidate slices (grid.x)
#define CPS (NN / SL)        // 512 candidates per slice
#define TILES (CPS / 64)     // 8 tiles per block (64 rows each)
#define IMAX 0x7fffffff

typedef __attribute__((ext_vector_type(4))) float f32x4;
typedef __attribute__((ext_vector_type(2))) long long2_t;
typedef __attribute__((ext_vector_type(8))) int i32x8;
typedef unsigned int u32;
typedef unsigned char u8;

// ---- software RNE fp32 -> OCP e4m3fn (no inf; max 448; bias 7) ----
static __device__ __forceinline__ u8 f2e4m3(float x) {
    float a = fabsf(x);
    a = fminf(a, 448.0f);
    const u32 s = (__float_as_uint(x) >> 31) << 7;
    if (a < 0.015625f) {                      // subnormal range: step 2^-9
        const int m = (int)rintf(a * 512.0f); // 0..8 (8 carries into exp=1 naturally)
        return (u8)(s | m);
    }
    u32 u = __float_as_uint(a);
    u += 0x7FFFF + ((u >> 20) & 1);           // RNE into 3-bit mantissa
    const u32 e = (u >> 23) - 120;            // -127 + 7
    return (u8)(s | (e << 3) | ((u >> 20) & 7));
}

static __device__ __forceinline__ i32x8 pack8(long2_t lo, long2_t hi) {
    union { long2_t l2[2]; i32x8 v; } u;
    u.l2[0] = lo; u.l2[1] = hi;
    return u.v;
}

// builtin's size/offset must be LITERAL constants
#define GLOAD16(g, l)                                                             \
    __builtin_amdgcn_global_load_lds(                                             \
        (const __attribute__((address_space(1))) void*)(g),                       \
        (__attribute__((address_space(3))) void*)(l), 16, 0, 0)

// ---------- kernel 1: fused kprep (blocks 0..2047) + kclass (2048..2175) ----------
static __device__ __forceinline__ void comb2(int& a1, int& a2, int b1, int b2) {
    const int lo = min(a1, b1);
    const int hi = max(a1, b1);
    a2 = min(hi, min(a2, b2));
    a1 = lo;
}

__global__ void kprepclass(const float* __restrict__ emb, const int* __restrict__ labels,
                           u8* __restrict__ E8, float* __restrict__ invn,
                           int* __restrict__ posidx, u32* __restrict__ cnt_done) {
    const int tid = threadIdx.x;
    if (blockIdx.x < 2048) {   // ---- kprep: normalized fp8 rows (plain layout) ----
        const int wid = tid >> 6, l = tid & 63;
        const int row = blockIdx.x * 4 + wid;
        const float4 v = *(const float4*)&emb[(size_t)row * DD + l * 4];
        float ss = v.x * v.x + v.y * v.y + v.z * v.z + v.w * v.w;
#pragma unroll
        for (int o = 1; o < 64; o <<= 1) ss += __shfl_xor(ss, o);
        const float inv = 1.0f / fmaxf(sqrtf(ss), 1e-12f);
        if (l == 0) invn[row] = inv;
        const u32 b0 = f2e4m3(v.x * inv), b1 = f2e4m3(v.y * inv);
        const u32 b2 = f2e4m3(v.z * inv), b3 = f2e4m3(v.w * inv);
        const u32 packed = b0 | (b1 << 8) | (b2 << 16) | (b3 << 24);
        *(u32*)&E8[(size_t)row * DD + l * 4] = packed;   // linear: A/B read identically
    } else {                   // ---- kclass ----
        const int c = blockIdx.x - 2048;
        if (c == 0 && tid == 0) *cnt_done = 0;   // arm the combine-final counter
        int m1 = IMAX, m2 = IMAX;
        for (int j = tid; j < NN; j += 256) {
            if (labels[j] == c) {
                if (m1 == IMAX) m1 = j;
                else if (m2 == IMAX) m2 = j;
            }
        }
#pragma unroll
        for (int o = 1; o < 64; o <<= 1)
            comb2(m1, m2, __shfl_xor(m1, o), __shfl_xor(m2, o));
        __shared__ int s1[4], s2[4];
        __shared__ int bj1, bj2;
        const int wave = tid >> 6, lane = tid & 63;
        if (lane == 0) { s1[wave] = m1; s2[wave] = m2; }
        __syncthreads();
        if (tid == 0) {
            comb2(m1, m2, s1[1], s2[1]);
            comb2(m1, m2, s1[2], s2[2]);
            comb2(m1, m2, s1[3], s2[3]);
            bj1 = m1; bj2 = m2;
        }
        __syncthreads();
        const int j1 = bj1, j2 = bj2;
        for (int j = tid; j < NN; j += 256)
            if (labels[j] == c) posidx[j] = (j2 == IMAX) ? -1 : ((j == j1) ? j2 : j1);
    }
}

// ---------- kernel 3: exact fp32 d_ap ----------
__global__ void kdap(const float* __restrict__ emb, const float* __restrict__ invn,
                     const int* __restrict__ posidx, float* __restrict__ dap) {
    const int wid = threadIdx.x >> 6, l = threadIdx.x & 63;
    const int i = blockIdx.x * 4 + wid;
    const int p = posidx[i];
    float dv = 0.0f;
    if (p >= 0) {   // uniform per wave
        const float4 a = *(const float4*)&emb[(size_t)i * DD + l * 4];
        const float4 b = *(const float4*)&emb[(size_t)p * DD + l * 4];
        float s = a.x * b.x + a.y * b.y + a.z * b.z + a.w * b.w;
#pragma unroll
        for (int o = 1; o < 64; o <<= 1) s += __shfl_xor(s, o);
        const float sim = s * invn[i] * invn[p];
        dv = fminf(fmaxf(1.0f - sim, 0.0f), 2.0f);
    }
    if (l == 0) dap[i] = dv;
}

// ---------- kernel 4: MX-scaled fp8 MFMA mining — R19 minus s_setprio ----------
// Identical to R19 (champion, 52.6 us) except the s_setprio(1)/(0) pair around
// each MFMA cluster is removed: T5 is null-to-negative on lockstep barrier
// schedules (m190), and the intrinsic can fence the scheduler's load/MFMA
// interleave. Single-variable A/B on the winning kernel.
__global__ __launch_bounds__(256, 3) void kmine(
    const u8* __restrict__ E8, const int* __restrict__ labels,
    const float* __restrict__ dap, float* __restrict__ pM1, float* __restrict__ pMN)
{
    __shared__ __align__(16) u8 At0[64 * 256], At1[64 * 256];   // 16 KB each
    __shared__ __align__(16) int Ls[CPS];                       // 2 KB labels
    __shared__ float RedN[2][128], RedS[2][128];

    const int tid = threadIdx.x;
    const int l = tid & 63;
    const int wid = tid >> 6;
    const int wr = wid >> 1;      // candidate half (M): rows wr*32..
    const int wc = wid & 1;       // anchor half (N): anchors wc*64..
    const int slice = blockIdx.x;
    const int a0 = blockIdx.y * 128;

    const int frow = l & 15;      // row within 16x16 subtile
    const int fq = l >> 4;        // 32-B k-group 0..3 within a K=128 half

    // --- prologue: labels -> LDS, per-anchor consts, B -> registers ---
    if (tid < 128) {
        const int4 lv = *(const int4*)&labels[slice * CPS + tid * 4];
        *(int4*)&Ls[tid * 4] = lv;
    }
    int la[4]; float hiv[4];
#pragma unroll
    for (int n = 0; n < 4; ++n) {
        const int ai = a0 + wc * 64 + n * 16 + frow;
        la[n] = labels[ai];
        hiv[n] = 1.0f - dap[ai];
    }
    const char* Ec = (const char*)E8;
    i32x8 breg[4][2];             // [n][kh] -> 64 VGPR
#pragma unroll
    for (int n = 0; n < 4; ++n)
#pragma unroll
        for (int kh = 0; kh < 2; ++kh) {
            const char* p = Ec + (size_t)(a0 + wc * 64 + n * 16 + frow) * 256
                               + kh * 128 + fq * 32;
            breg[n][kh] = pack8(*(const long2_t*)p, *(const long2_t*)(p + 16));
        }

    // A staging: thread t stages physical chunk P=(t&15) of rows (t>>4 + 16i);
    // source logical chunk C = P ^ (row&15) = (t&15)^(t>>4) — constant per thread.
    const char* asrc = Ec + ((size_t)(slice * CPS) + (tid >> 4)) * 256
                          + (((tid & 15) ^ (tid >> 4)) * 16);

#define STAGE(BUF, OFF) do {                                    \
        _Pragma("unroll")                                       \
        for (int i = 0; i < 4; ++i)                             \
            GLOAD16(asrc + (OFF) + i * 4096,                    \
                    &BUF[tid * 16 + i * 4096]);                 \
    } while (0)

    float mN[4], m1[4];
#pragma unroll
    for (int n = 0; n < 4; ++n) { mN[n] = -INFINITY; m1[n] = -INFINITY; }
    const f32x4 Zv = {0.f, 0.f, 0.f, 0.f};
    f32x4 acc[2][4];

    // compute one 64-row tile (K=256 = 2 scaled-MFMA per m,n) + running maxes
#define COMPTILE(BUF, T) do {                                                       \
        _Pragma("unroll")                                                           \
        for (int kh = 0; kh < 2; ++kh) {                                            \
            i32x8 a8[2];                                                            \
            _Pragma("unroll")                                                       \
            for (int m = 0; m < 2; ++m) {                                           \
                const int row = wr * 32 + m * 16 + frow;                            \
                const int cb = kh * 8 + fq * 2;                                     \
                const int p0 = (cb ^ (row & 15)) * 16;                              \
                const int p1 = ((cb + 1) ^ (row & 15)) * 16;                        \
                a8[m] = pack8(*(const long2_t*)&BUF[row * 256 + p0],                \
                              *(const long2_t*)&BUF[row * 256 + p1]);               \
            }                                                                       \
            _Pragma("unroll")                                                       \
            for (int m = 0; m < 2; ++m)                                             \
                _Pragma("unroll")                                                   \
                for (int n = 0; n < 4; ++n)                                         \
                    acc[m][n] = __builtin_amdgcn_mfma_scale_f32_16x16x128_f8f6f4(   \
                        a8[m], breg[n][kh], (kh == 0) ? Zv : acc[m][n],             \
                        0, 0, 0, 0x7F7F7F7F, 0, 0x7F7F7F7F);                        \
        }                                                                           \
        {                                                                           \
            int lcv[8];                                                             \
            _Pragma("unroll")                                                       \
            for (int m = 0; m < 2; ++m) {                                           \
                const int4 v = *(const int4*)&Ls[(T) * 64 + wr * 32 + m * 16        \
                                                 + fq * 4];                        \
                lcv[m * 4 + 0] = v.x; lcv[m * 4 + 1] = v.y;                         \
                lcv[m * 4 + 2] = v.z; lcv[m * 4 + 3] = v.w;                         \
            }                                                                       \
            _Pragma("unroll")                                                       \
            for (int n = 0; n < 4; ++n) {                                           \
                _Pragma("unroll")                                                   \
                for (int m = 0; m < 2; ++m)                                         \
                    _Pragma("unroll")                                               \
                    for (int r = 0; r < 4; ++r) {                                   \
                        const float sv = acc[m][n][r];                              \
                        const float sel = (lcv[m * 4 + r] != la[n]) ? sv            \
                                                                    : -INFINITY;    \
                        mN[n] = fmaxf(mN[n], sel);                                  \
                        m1[n] = fmaxf(m1[n], (sel < hiv[n]) ? sel : -INFINITY);     \
                    }                                                               \
            }                                                                       \
        }                                                                           \
    } while (0)

    // prologue: stage tile 0; drain lgkm (labels ds_write) before first barrier
    STAGE(At0, 0);
    asm volatile("s_waitcnt lgkmcnt(0)" ::: "memory");

#pragma unroll
    for (int t = 0; t < TILES; ++t) {
        if (t + 1 < TILES) {
            if (t & 1) STAGE(At0, (t + 1) * 16384);
            else       STAGE(At1, (t + 1) * 16384);
        }
        if (t + 1 < TILES)
            asm volatile("s_waitcnt vmcnt(4)" ::: "memory");
        else
            asm volatile("s_waitcnt vmcnt(0)" ::: "memory");
        __builtin_amdgcn_s_barrier();
        if (t & 1) COMPTILE(At1, t);
        else       COMPTILE(At0, t);
        __builtin_amdgcn_s_barrier();   // frees the just-computed buffer
    }
#undef STAGE
#undef COMPTILE

    // reduce the 4 candidate row-groups (lanes l, l^16, l^32, l^48 share anchor)
#pragma unroll
    for (int n = 0; n < 4; ++n) {
        mN[n] = fmaxf(mN[n], __shfl_xor(mN[n], 16));
        mN[n] = fmaxf(mN[n], __shfl_xor(mN[n], 32));
        m1[n] = fmaxf(m1[n], __shfl_xor(m1[n], 16));
        m1[n] = fmaxf(m1[n], __shfl_xor(m1[n], 32));
    }
    __syncthreads();
    // combine the two candidate halves via LDS max (wr = 0,1)
    if (fq == 0) {
#pragma unroll
        for (int n = 0; n < 4; ++n) {
            if (wr == 0) {
                RedN[0][wc * 64 + n * 16 + frow] = mN[n];
                RedS[0][wc * 64 + n * 16 + frow] = m1[n];
            } else {
                RedN[1][wc * 64 + n * 16 + frow] = mN[n];
                RedS[1][wc * 64 + n * 16 + frow] = m1[n];
            }
        }
    }
    __syncthreads();
    if (tid < 128) {
        pMN[slice * NN + a0 + tid] = fmaxf(RedN[0][tid], RedN[1][tid]);
        pM1[slice * NN + a0 + tid] = fmaxf(RedS[0][tid], RedS[1][tid]);
    }
}

// ---------- kernel 5: combine slices + fused final scalar ----------
__global__ void kcombine(const int* __restrict__ posidx, const float* __restrict__ dap,
                         const float* __restrict__ pM1, const float* __restrict__ pMN,
                         float* __restrict__ partials, u32* __restrict__ cnt_done,
                         float* __restrict__ out)
{
    const int i = blockIdx.x * 256 + threadIdx.x;
    float loss = 0.0f, cnt = 0.0f;
    if (posidx[i] >= 0) {
        float s1 = -INFINITY, sN = -INFINITY;
#pragma unroll
        for (int s = 0; s < SL; ++s) {
            s1 = fmaxf(s1, pM1[s * NN + i]);
            sN = fmaxf(sN, pMN[s * NN + i]);
        }
        const float da = dap[i];
        const float lo = 1.0f - da - MARGIN;
        const float M = (s1 > lo) ? s1 : sN;   // has_semi ? best semi : hardest
        const float dan = fminf(fmaxf(1.0f - M, 0.0f), 2.0f);
        loss = fmaxf(da - dan + MARGIN, 0.0f);
        cnt = 1.0f;
    }
#pragma unroll
    for (int off = 1; off < 64; off <<= 1) {
        loss += __shfl_xor(loss, off);
        cnt  += __shfl_xor(cnt, off);
    }
    __shared__ float sl[4], sc[4];
    __shared__ int last;
    const int wave = threadIdx.x >> 6, lane = threadIdx.x & 63;
    if (lane == 0) { sl[wave] = loss; sc[wave] = cnt; }
    __syncthreads();
    if (threadIdx.x == 0) {
        partials[blockIdx.x]      = sl[0] + sl[1] + sl[2] + sl[3];
        partials[32 + blockIdx.x] = sc[0] + sc[1] + sc[2] + sc[3];
        __threadfence();
        last = (atomicAdd(cnt_done, 1u) == 31u);   // device-scope, cross-XCD safe
    }
    __syncthreads();
    if (last && threadIdx.x < 64) {   // last block reduces all partials
        const int t = threadIdx.x;
        float L = (t < 32) ? partials[t] : 0.0f;
        float C = (t < 32) ? partials[32 + t] : 0.0f;
#pragma unroll
        for (int off = 1; off < 64; off <<= 1) {
            L += __shfl_xor(L, off);
            C += __shfl_xor(C, off);
        }
        if (t == 0) out[0] = (C > 0.0f) ? (L / C) : 0.0f;
    }
}

extern "C" void kernel_launch(void* const* d_in, const int* in_sizes, int n_in,
                              void* d_out, int out_size, void* d_ws, size_t ws_size,
                              hipStream_t stream) {
    const float* emb  = (const float*)d_in[0];
    const int* labels = (const int*)d_in[1];
    float* out = (float*)d_out;

    char* w = (char*)d_ws;
    u8*    E8   = (u8*)w;                        w += (size_t)NN * DD;       // 2 MB
    float* invn = (float*)w;                     w += NN * 4;
    float* dapv = (float*)w;                     w += NN * 4;
    int*   posi = (int*)w;                       w += NN * 4;
    float* pM1  = (float*)w;                     w += (size_t)SL * NN * 4;   // 512 KB
    float* pMN  = (float*)w;                     w += (size_t)SL * NN * 4;   // 512 KB
    float* parts = (float*)w;                    w += 64 * 4;
    u32*   cdone = (u32*)w;

    kprepclass<<<2048 + 128, 256, 0, stream>>>(emb, labels, E8, invn, posi, cdone);
    kdap<<<NN / 4, 256, 0, stream>>>(emb, invn, posi, dapv);
    kmine<<<dim3(SL, NN / 128), 256, 0, stream>>>(E8, labels, dapv, pM1, pMN);
    kcombine<<<NN / 256, 256, 0, stream>>>(posi, dapv, pM1, pMN, parts, cdone, out);
}

// Round 23
// 52.422 us; speedup vs baseline: 1.0847x; 1.0367x over previous
//
#include <hip/hip_runtime.h>
#include <math.h>

#define NN 8192
#define DD 256
#define MARGIN 0.2f
#define SL 16                // candidate slices (grid.x)
#define CPS (NN / SL)        // 512 candidates per slice
#define TILES (CPS / 64)     // 8 tiles per block (64 rows each)
#define IMAX 0x7fffffff

typedef __attribute__((ext_vector_type(4))) float f32x4;
typedef __attribute__((ext_vector_type(2))) long long2_t;
typedef __attribute__((ext_vector_type(8))) int i32x8;
typedef unsigned int u32;
typedef unsigned char u8;

// ---- software RNE fp32 -> OCP e4m3fn (no inf; max 448; bias 7) ----
static __device__ __forceinline__ u8 f2e4m3(float x) {
    float a = fabsf(x);
    a = fminf(a, 448.0f);
    const u32 s = (__float_as_uint(x) >> 31) << 7;
    if (a < 0.015625f) {                      // subnormal range: step 2^-9
        const int m = (int)rintf(a * 512.0f); // 0..8 (8 carries into exp=1 naturally)
        return (u8)(s | m);
    }
    u32 u = __float_as_uint(a);
    u += 0x7FFFF + ((u >> 20) & 1);           // RNE into 3-bit mantissa
    const u32 e = (u >> 23) - 120;            // -127 + 7
    return (u8)(s | (e << 3) | ((u >> 20) & 7));
}

static __device__ __forceinline__ i32x8 pack8(long2_t lo, long2_t hi) {
    union { long2_t l2[2]; i32x8 v; } u;
    u.l2[0] = lo; u.l2[1] = hi;
    return u.v;
}

// builtin's size/offset must be LITERAL constants
#define GLOAD16(g, l)                                                             \
    __builtin_amdgcn_global_load_lds(                                             \
        (const __attribute__((address_space(1))) void*)(g),                       \
        (__attribute__((address_space(3))) void*)(l), 16, 0, 0)

// ---------- kernel 1: fused kprep (blocks 0..2047) + kclass (2048..2175) ----------
static __device__ __forceinline__ void comb2(int& a1, int& a2, int b1, int b2) {
    const int lo = min(a1, b1);
    const int hi = max(a1, b1);
    a2 = min(hi, min(a2, b2));
    a1 = lo;
}

__global__ void kprepclass(const float* __restrict__ emb, const int* __restrict__ labels,
                           u8* __restrict__ E8, float* __restrict__ invn,
                           int* __restrict__ posidx, u32* __restrict__ cnt_done) {
    const int tid = threadIdx.x;
    if (blockIdx.x < 2048) {   // ---- kprep: normalized fp8 rows (plain layout) ----
        const int wid = tid >> 6, l = tid & 63;
        const int row = blockIdx.x * 4 + wid;
        const float4 v = *(const float4*)&emb[(size_t)row * DD + l * 4];
        float ss = v.x * v.x + v.y * v.y + v.z * v.z + v.w * v.w;
#pragma unroll
        for (int o = 1; o < 64; o <<= 1) ss += __shfl_xor(ss, o);
        const float inv = 1.0f / fmaxf(sqrtf(ss), 1e-12f);
        if (l == 0) invn[row] = inv;
        const u32 b0 = f2e4m3(v.x * inv), b1 = f2e4m3(v.y * inv);
        const u32 b2 = f2e4m3(v.z * inv), b3 = f2e4m3(v.w * inv);
        const u32 packed = b0 | (b1 << 8) | (b2 << 16) | (b3 << 24);
        *(u32*)&E8[(size_t)row * DD + l * 4] = packed;   // linear: A/B read identically
    } else {                   // ---- kclass ----
        const int c = blockIdx.x - 2048;
        if (c == 0 && tid == 0) *cnt_done = 0;   // arm the combine-final counter
        int m1 = IMAX, m2 = IMAX;
        for (int j = tid; j < NN; j += 256) {
            if (labels[j] == c) {
                if (m1 == IMAX) m1 = j;
                else if (m2 == IMAX) m2 = j;
            }
        }
#pragma unroll
        for (int o = 1; o < 64; o <<= 1)
            comb2(m1, m2, __shfl_xor(m1, o), __shfl_xor(m2, o));
        __shared__ int s1[4], s2[4];
        __shared__ int bj1, bj2;
        const int wave = tid >> 6, lane = tid & 63;
        if (lane == 0) { s1[wave] = m1; s2[wave] = m2; }
        __syncthreads();
        if (tid == 0) {
            comb2(m1, m2, s1[1], s2[1]);
            comb2(m1, m2, s1[2], s2[2]);
            comb2(m1, m2, s1[3], s2[3]);
            bj1 = m1; bj2 = m2;
        }
        __syncthreads();
        const int j1 = bj1, j2 = bj2;
        for (int j = tid; j < NN; j += 256)
            if (labels[j] == c) posidx[j] = (j2 == IMAX) ? -1 : ((j == j1) ? j2 : j1);
    }
}

// ---------- kernel 3: exact fp32 d_ap ----------
__global__ void kdap(const float* __restrict__ emb, const float* __restrict__ invn,
                     const int* __restrict__ posidx, float* __restrict__ dap) {
    const int wid = threadIdx.x >> 6, l = threadIdx.x & 63;
    const int i = blockIdx.x * 4 + wid;
    const int p = posidx[i];
    float dv = 0.0f;
    if (p >= 0) {   // uniform per wave
        const float4 a = *(const float4*)&emb[(size_t)i * DD + l * 4];
        const float4 b = *(const float4*)&emb[(size_t)p * DD + l * 4];
        float s = a.x * b.x + a.y * b.y + a.z * b.z + a.w * b.w;
#pragma unroll
        for (int o = 1; o < 64; o <<= 1) s += __shfl_xor(s, o);
        const float sim = s * invn[i] * invn[p];
        dv = fminf(fmaxf(1.0f - sim, 0.0f), 2.0f);
    }
    if (l == 0) dap[i] = dv;
}

// ---------- kernel 4: MX-scaled fp8 MFMA mining — champion configuration (R19) ----
// 64-row A-tiles double-buffered (16 KB each), counted vmcnt(4) (depth-1), 2
// barriers/tile, chunk swizzle P = C^(row&15) (0 conflicts), B in 64 VGPR,
// identity-scale mfma_scale_f32_16x16x128_f8f6f4, launch_bounds(256,3), setprio.
__global__ __launch_bounds__(256, 3) void kmine(
    const u8* __restrict__ E8, const int* __restrict__ labels,
    const float* __restrict__ dap, float* __restrict__ pM1, float* __restrict__ pMN)
{
    __shared__ __align__(16) u8 At0[64 * 256], At1[64 * 256];   // 16 KB each
    __shared__ __align__(16) int Ls[CPS];                       // 2 KB labels
    __shared__ float RedN[2][128], RedS[2][128];

    const int tid = threadIdx.x;
    const int l = tid & 63;
    const int wid = tid >> 6;
    const int wr = wid >> 1;      // candidate half (M): rows wr*32..
    const int wc = wid & 1;       // anchor half (N): anchors wc*64..
    const int slice = blockIdx.x;
    const int a0 = blockIdx.y * 128;

    const int frow = l & 15;      // row within 16x16 subtile
    const int fq = l >> 4;        // 32-B k-group 0..3 within a K=128 half

    // --- prologue: labels -> LDS, per-anchor consts, B -> registers ---
    if (tid < 128) {
        const int4 lv = *(const int4*)&labels[slice * CPS + tid * 4];
        *(int4*)&Ls[tid * 4] = lv;
    }
    int la[4]; float hiv[4];
#pragma unroll
    for (int n = 0; n < 4; ++n) {
        const int ai = a0 + wc * 64 + n * 16 + frow;
        la[n] = labels[ai];
        hiv[n] = 1.0f - dap[ai];
    }
    const char* Ec = (const char*)E8;
    i32x8 breg[4][2];             // [n][kh] -> 64 VGPR
#pragma unroll
    for (int n = 0; n < 4; ++n)
#pragma unroll
        for (int kh = 0; kh < 2; ++kh) {
            const char* p = Ec + (size_t)(a0 + wc * 64 + n * 16 + frow) * 256
                               + kh * 128 + fq * 32;
            breg[n][kh] = pack8(*(const long2_t*)p, *(const long2_t*)(p + 16));
        }

    // A staging: thread t stages physical chunk P=(t&15) of rows (t>>4 + 16i);
    // source logical chunk C = P ^ (row&15) = (t&15)^(t>>4) — constant per thread.
    const char* asrc = Ec + ((size_t)(slice * CPS) + (tid >> 4)) * 256
                          + (((tid & 15) ^ (tid >> 4)) * 16);

#define STAGE(BUF, OFF) do {                                    \
        _Pragma("unroll")                                       \
        for (int i = 0; i < 4; ++i)                             \
            GLOAD16(asrc + (OFF) + i * 4096,                    \
                    &BUF[tid * 16 + i * 4096]);                 \
    } while (0)

    float mN[4], m1[4];
#pragma unroll
    for (int n = 0; n < 4; ++n) { mN[n] = -INFINITY; m1[n] = -INFINITY; }
    const f32x4 Zv = {0.f, 0.f, 0.f, 0.f};
    f32x4 acc[2][4];

    // compute one 64-row tile (K=256 = 2 scaled-MFMA per m,n) + running maxes
#define COMPTILE(BUF, T) do {                                                       \
        _Pragma("unroll")                                                           \
        for (int kh = 0; kh < 2; ++kh) {                                            \
            i32x8 a8[2];                                                            \
            _Pragma("unroll")                                                       \
            for (int m = 0; m < 2; ++m) {                                           \
                const int row = wr * 32 + m * 16 + frow;                            \
                const int cb = kh * 8 + fq * 2;                                     \
                const int p0 = (cb ^ (row & 15)) * 16;                              \
                const int p1 = ((cb + 1) ^ (row & 15)) * 16;                        \
                a8[m] = pack8(*(const long2_t*)&BUF[row * 256 + p0],                \
                              *(const long2_t*)&BUF[row * 256 + p1]);               \
            }                                                                       \
            __builtin_amdgcn_s_setprio(1);                                          \
            _Pragma("unroll")                                                       \
            for (int m = 0; m < 2; ++m)                                             \
                _Pragma("unroll")                                                   \
                for (int n = 0; n < 4; ++n)                                         \
                    acc[m][n] = __builtin_amdgcn_mfma_scale_f32_16x16x128_f8f6f4(   \
                        a8[m], breg[n][kh], (kh == 0) ? Zv : acc[m][n],             \
                        0, 0, 0, 0x7F7F7F7F, 0, 0x7F7F7F7F);                        \
            __builtin_amdgcn_s_setprio(0);                                          \
        }                                                                           \
        {                                                                           \
            int lcv[8];                                                             \
            _Pragma("unroll")                                                       \
            for (int m = 0; m < 2; ++m) {                                           \
                const int4 v = *(const int4*)&Ls[(T) * 64 + wr * 32 + m * 16        \
                                                 + fq * 4];                        \
                lcv[m * 4 + 0] = v.x; lcv[m * 4 + 1] = v.y;                         \
                lcv[m * 4 + 2] = v.z; lcv[m * 4 + 3] = v.w;                         \
            }                                                                       \
            _Pragma("unroll")                                                       \
            for (int n = 0; n < 4; ++n) {                                           \
                _Pragma("unroll")                                                   \
                for (int m = 0; m < 2; ++m)                                         \
                    _Pragma("unroll")                                               \
                    for (int r = 0; r < 4; ++r) {                                   \
                        const float sv = acc[m][n][r];                              \
                        const float sel = (lcv[m * 4 + r] != la[n]) ? sv            \
                                                                    : -INFINITY;    \
                        mN[n] = fmaxf(mN[n], sel);                                  \
                        m1[n] = fmaxf(m1[n], (sel < hiv[n]) ? sel : -INFINITY);     \
                    }                                                               \
            }                                                                       \
        }                                                                           \
    } while (0)

    // prologue: stage tile 0; drain lgkm (labels ds_write) before first barrier
    STAGE(At0, 0);
    asm volatile("s_waitcnt lgkmcnt(0)" ::: "memory");

#pragma unroll
    for (int t = 0; t < TILES; ++t) {
        if (t + 1 < TILES) {
            if (t & 1) STAGE(At0, (t + 1) * 16384);
            else       STAGE(At1, (t + 1) * 16384);
        }
        if (t + 1 < TILES)
            asm volatile("s_waitcnt vmcnt(4)" ::: "memory");
        else
            asm volatile("s_waitcnt vmcnt(0)" ::: "memory");
        __builtin_amdgcn_s_barrier();
        if (t & 1) COMPTILE(At1, t);
        else       COMPTILE(At0, t);
        __builtin_amdgcn_s_barrier();   // frees the just-computed buffer
    }
#undef STAGE
#undef COMPTILE

    // reduce the 4 candidate row-groups (lanes l, l^16, l^32, l^48 share anchor)
#pragma unroll
    for (int n = 0; n < 4; ++n) {
        mN[n] = fmaxf(mN[n], __shfl_xor(mN[n], 16));
        mN[n] = fmaxf(mN[n], __shfl_xor(mN[n], 32));
        m1[n] = fmaxf(m1[n], __shfl_xor(m1[n], 16));
        m1[n] = fmaxf(m1[n], __shfl_xor(m1[n], 32));
    }
    __syncthreads();
    // combine the two candidate halves via LDS max (wr = 0,1)
    if (fq == 0) {
#pragma unroll
        for (int n = 0; n < 4; ++n) {
            if (wr == 0) {
                RedN[0][wc * 64 + n * 16 + frow] = mN[n];
                RedS[0][wc * 64 + n * 16 + frow] = m1[n];
            } else {
                RedN[1][wc * 64 + n * 16 + frow] = mN[n];
                RedS[1][wc * 64 + n * 16 + frow] = m1[n];
            }
        }
    }
    __syncthreads();
    if (tid < 128) {
        pMN[slice * NN + a0 + tid] = fmaxf(RedN[0][tid], RedN[1][tid]);
        pM1[slice * NN + a0 + tid] = fmaxf(RedS[0][tid], RedS[1][tid]);
    }
}

// ---------- kernel 5: combine slices + fused final scalar ----------
__global__ void kcombine(const int* __restrict__ posidx, const float* __restrict__ dap,
                         const float* __restrict__ pM1, const float* __restrict__ pMN,
                         float* __restrict__ partials, u32* __restrict__ cnt_done,
                         float* __restrict__ out)
{
    const int i = blockIdx.x * 256 + threadIdx.x;
    float loss = 0.0f, cnt = 0.0f;
    if (posidx[i] >= 0) {
        float s1 = -INFINITY, sN = -INFINITY;
#pragma unroll
        for (int s = 0; s < SL; ++s) {
            s1 = fmaxf(s1, pM1[s * NN + i]);
            sN = fmaxf(sN, pMN[s * NN + i]);
        }
        const float da = dap[i];
        const float lo = 1.0f - da - MARGIN;
        const float M = (s1 > lo) ? s1 : sN;   // has_semi ? best semi : hardest
        const float dan = fminf(fmaxf(1.0f - M, 0.0f), 2.0f);
        loss = fmaxf(da - dan + MARGIN, 0.0f);
        cnt = 1.0f;
    }
#pragma unroll
    for (int off = 1; off < 64; off <<= 1) {
        loss += __shfl_xor(loss, off);
        cnt  += __shfl_xor(cnt, off);
    }
    __shared__ float sl[4], sc[4];
    __shared__ int last;
    const int wave = threadIdx.x >> 6, lane = threadIdx.x & 63;
    if (lane == 0) { sl[wave] = loss; sc[wave] = cnt; }
    __syncthreads();
    if (threadIdx.x == 0) {
        partials[blockIdx.x]      = sl[0] + sl[1] + sl[2] + sl[3];
        partials[32 + blockIdx.x] = sc[0] + sc[1] + sc[2] + sc[3];
        __threadfence();
        last = (atomicAdd(cnt_done, 1u) == 31u);   // device-scope, cross-XCD safe
    }
    __syncthreads();
    if (last && threadIdx.x < 64) {   // last block reduces all partials
        const int t = threadIdx.x;
        float L = (t < 32) ? partials[t] : 0.0f;
        float C = (t < 32) ? partials[32 + t] : 0.0f;
#pragma unroll
        for (int off = 1; off < 64; off <<= 1) {
            L += __shfl_xor(L, off);
            C += __shfl_xor(C, off);
        }
        if (t == 0) out[0] = (C > 0.0f) ? (L / C) : 0.0f;
    }
}

extern "C" void kernel_launch(void* const* d_in, const int* in_sizes, int n_in,
                              void* d_out, int out_size, void* d_ws, size_t ws_size,
                              hipStream_t stream) {
    const float* emb  = (const float*)d_in[0];
    const int* labels = (const int*)d_in[1];
    float* out = (float*)d_out;

    char* w = (char*)d_ws;
    u8*    E8   = (u8*)w;                        w += (size_t)NN * DD;       // 2 MB
    float* invn = (float*)w;                     w += NN * 4;
    float* dapv = (float*)w;                     w += NN * 4;
    int*   posi = (int*)w;                       w += NN * 4;
    float* pM1  = (float*)w;                     w += (size_t)SL * NN * 4;   // 512 KB
    float* pMN  = (float*)w;                     w += (size_t)SL * NN * 4;   // 512 KB
    float* parts = (float*)w;                    w += 64 * 4;
    u32*   cdone = (u32*)w;

    kprepclass<<<2048 + 128, 256, 0, stream>>>(emb, labels, E8, invn, posi, cdone);
    kdap<<<NN / 4, 256, 0, stream>>>(emb, invn, posi, dapv);
    kmine<<<dim3(SL, NN / 128), 256, 0, stream>>>(E8, labels, dapv, pM1, pMN);
    kcombine<<<NN / 256, 256, 0, stream>>>(posi, dapv, pM1, pMN, parts, cdone, out);
}